// Round 2
// baseline (311.063 us; speedup 1.0000x reference)
//
#include <hip/hip_runtime.h>

// Problem constants from the reference
constexpr int B_ = 32;
constexpr int S_ = 2048;
constexpr int F_ = 512;
constexpr int ROWS = B_ * S_;          // 65536 rows of length F=512
constexpr int WAVES_PER_BLOCK = 4;     // 256 threads
constexpr int ROWS_PER_WAVE = 4;       // 16 rows per block -> 4096 blocks

// out = one_hot(argmax_F(logits + gumbel)) per row.  (Reference's
// softmax/straight-through/top_k/scatter pipeline is the identity on the
// hard one-hot: non-argmax entries are exactly +0.0, and top_k(-mask, K)
// selects only already-zero entries since K < #zeros.)
//
// Structure (latency-oriented):
//   1. zero-stores for all 4 rows issue FIRST (no dependencies -> stream out
//      while loads are in flight)
//   2. all 16 loads issue (6 KB of reads in flight per wave)
//   3. per-row: add, 6-step max butterfly, ballot+ctz first-index argmax
//   4. single s_waitcnt vmcnt(0) drains every prior vmem (zero stores
//      included, FIFO), then one scalar 1.0f store per row
__global__ __launch_bounds__(256) void gumbel_hard_onehot_kernel(
    const float* __restrict__ logits,
    const float* __restrict__ gumbel,
    float* __restrict__ out)
{
    const int lane = threadIdx.x & 63;
    const int wave = threadIdx.x >> 6;
    const int rowbase = (blockIdx.x * WAVES_PER_BLOCK + wave) * ROWS_PER_WAVE;

    const size_t base_off = (size_t)rowbase * F_;
    const float4* __restrict__ lg = (const float4*)(logits + base_off);
    const float4* __restrict__ gm = (const float4*)(gumbel + base_off);
    float4* __restrict__ op = (float4*)(out + base_off);

    // --- 1) zero the whole 4-row output region (8 KB / wave), no deps ---
    const float4 z4 = make_float4(0.f, 0.f, 0.f, 0.f);
#pragma unroll
    for (int r = 0; r < ROWS_PER_WAVE; ++r) {
        op[r * 128 + lane]      = z4;
        op[r * 128 + lane + 64] = z4;
    }

    // --- 2) issue all loads (4 rows x 4 float4 = 6 KB reads in flight) ---
    float4 A0[ROWS_PER_WAVE], A1[ROWS_PER_WAVE], B0[ROWS_PER_WAVE], B1[ROWS_PER_WAVE];
#pragma unroll
    for (int r = 0; r < ROWS_PER_WAVE; ++r) {
        A0[r] = lg[r * 128 + lane];
        A1[r] = lg[r * 128 + lane + 64];
        B0[r] = gm[r * 128 + lane];
        B1[r] = gm[r * 128 + lane + 64];
    }

    // --- 3) per-row argmax ---
    int idxs[ROWS_PER_WAVE];
#pragma unroll
    for (int r = 0; r < ROWS_PER_WAVE; ++r) {
        float v[8];
        v[0] = A0[r].x + B0[r].x; v[1] = A0[r].y + B0[r].y;
        v[2] = A0[r].z + B0[r].z; v[3] = A0[r].w + B0[r].w;
        v[4] = A1[r].x + B1[r].x; v[5] = A1[r].y + B1[r].y;
        v[6] = A1[r].z + B1[r].z; v[7] = A1[r].w + B1[r].w;

        // local max of 8 (tree)
        float m01 = fmaxf(v[0], v[1]), m23 = fmaxf(v[2], v[3]);
        float m45 = fmaxf(v[4], v[5]), m67 = fmaxf(v[6], v[7]);
        float best = fmaxf(fmaxf(m01, m23), fmaxf(m45, m67));

        // wave-wide max (6-step butterfly, value only)
#pragma unroll
        for (int off = 32; off > 0; off >>= 1)
            best = fmaxf(best, __shfl_xor(best, off, 64));
        // all lanes: best == row max (exact — max is a selection)

        // first-index argmax: half0 holds indices 4*lane+j (j<4),
        // half1 holds 256+4*lane+j.  Smallest global index wins.
        int j0 = 4, j1 = 4;
#pragma unroll
        for (int j = 3; j >= 0; --j) {
            if (v[j] == best)     j0 = j;
            if (v[4 + j] == best) j1 = j;
        }
        unsigned long long b0 = __ballot(j0 < 4);
        unsigned long long b1 = __ballot(j1 < 4);
        int cand0 = 4 * lane + j0;          // valid where j0<4
        int cand1 = 256 + 4 * lane + j1;    // valid where j1<4

        int idx;
        if (b0) {
            int L = __builtin_ctzll(b0);
            idx = __shfl(cand0, L, 64);
        } else {
            int L = __builtin_ctzll(b1);
            idx = __shfl(cand1, L, 64);
        }
        idxs[r] = idx;
    }

    // --- 4) drain all prior vmem (zero stores included, vmcnt is FIFO),
    //        then write the four 1.0f entries ---
    __builtin_amdgcn_s_waitcnt(0x0F70);  // vmcnt(0), expcnt/lgkmcnt don't-care
    if (lane == 0) {
#pragma unroll
        for (int r = 0; r < ROWS_PER_WAVE; ++r)
            out[base_off + (size_t)r * F_ + idxs[r]] = 1.0f;
    }
}

extern "C" void kernel_launch(void* const* d_in, const int* in_sizes, int n_in,
                              void* d_out, int out_size, void* d_ws, size_t ws_size,
                              hipStream_t stream) {
    const float* logits = (const float*)d_in[0];
    const float* gumbel = (const float*)d_in[1];
    float* out = (float*)d_out;

    const int grid = ROWS / (WAVES_PER_BLOCK * ROWS_PER_WAVE);  // 4096 blocks
    gumbel_hard_onehot_kernel<<<grid, 256, 0, stream>>>(logits, gumbel, out);
}